// Round 5
// baseline (44.281 us; speedup 1.0000x reference)
//
#include <hip/hip_runtime.h>
#include <math.h>

// Batched tridiagonal solve A(exp(alpha)) u = f_rhs via chunked partition
// (SPIKE-style), one wave per row, solver in f64.
// Round 5: phase-1a rewritten DIVISION-FREE (continuant chains):
//   delta_i = b_i*delta_{i-1} - K_i^2*delta_{i-2}   (fma chain, 8cy/step)
//   phi_i   = K_i*phi_{i-1} + f_i*delta_{i-1}
//   psi_i   = psi_{i-1}*K_i
// then 16 INDEPENDENT rcp_f64 (pipelined) assemble c'=-(K+)d<,u~=phi/d,v=psi/d.
// Replaces the 16-step chained fma->rcp->mul elimination (~45cy/step) that
// made round 4 latency-bound (VALUBusy 44%). Phases 1b/2/3 verbatim from the
// passing round-4 kernel. All f64 entries derive exactly from f32 K values,
// so the dominant (K-quantization) error term is unchanged.

constexpr int BT   = 16384;
constexpr int MPTS = 1024;
constexpr int NU   = 1023;   // real unknowns
constexpr int CS   = 16;     // chunk size (per lane)
constexpr int WPB  = 4;      // rows (waves) per block

__device__ __forceinline__ double fast_rcp(double x) {
    double r = __builtin_amdgcn_rcp(x);       // v_rcp_f64, ~2^-27
    r = fma(r, fma(-x, r, 1.0), r);           // 1 NR -> ~2^-54
    return r;
}

__global__ __launch_bounds__(WPB * 64, 3)
void pt_kernel(const float* __restrict__ alpha,
               const float* __restrict__ f_rhs,
               float* __restrict__ out) {
    const int t    = threadIdx.x;
    const int lane = t & 63;
    const int w    = t >> 6;
    const int row  = blockIdx.x * WPB + w;
    const int s    = lane * CS;          // first global index of this chunk

    __shared__ float ostage[WPB][NU + (NU >> 5) + 2];
    __shared__ float f_lds[1056];        // swizzled: f[j] at j + (j>>5)

    // Stage f_rhs once per block (swizzled, 2-way-conflict-free reads).
    for (int i = t; i < NU; i += WPB * 64) f_lds[i + (i >> 5)] = f_rhs[i];
    if (t == 0) f_lds[1023 + (1023 >> 5)] = 0.0f;  // identity-pad row: f = 0

    // ---------------- load K = exp(alpha) for this chunk (17 values) --------
    const float* arow = alpha + (size_t)row * MPTS;
    float kf[CS + 1];
    #pragma unroll
    for (int q = 0; q < 4; ++q) {
        const float4 v = *reinterpret_cast<const float4*>(arow + s + 4 * q);
        kf[4 * q + 0] = expf(v.x);
        kf[4 * q + 1] = expf(v.y);
        kf[4 * q + 2] = expf(v.z);
        kf[4 * q + 3] = expf(v.w);
    }
    {
        float kx = (lane < 63) ? arow[s + CS] : 0.0f;  // lane63: exp(0)=1
        kf[CS] = expf(kx);
    }
    // lane 63 pre-patch: kn at j=1022 -> 0 gives b=kc, d=0 there; at j=1023
    // kc=0, kn=1 gives the identity row (b=1) with f=0.
    if (lane == 63) kf[15] = 0.0f;

    __syncthreads();  // f_lds ready

    // ---------------- phase 1a: division-free continuant chains -------------
    // delta chain (2-term), phi chain, psi running product. All fma/mul,
    // 8cy/step dependent latency; no divisions on the chain.
    double dlv[CS], phv[CS], psv[CS];
    {
        double dm1 = 1.0, dm2 = 0.0;   // delta_{i-1}, delta_{i-2}
        double phm = 0.0;              // phi_{i-1}
        double psm = 1.0;              // psi_{i-1}
        #pragma unroll
        for (int i = 0; i < CS; ++i) {
            const int j = s + i;
            const double kc = (double)kf[i];
            const double kn = (double)kf[i + 1];
            double b = kc + kn;
            if (i == 0) b = (lane == 0) ? (2.0 * kc + kn) : b;  // j=0 boundary
            const double tq = kc * kc;                 // a_i * d_{i-1} = K_i^2
            const double fv = (double)f_lds[j + (j >> 5)];
            const double dv = fma(b, dm1, -(tq * dm2));
            const double pv = fma(kc, phm, fv * dm1);
            const double sv = psm * kc;
            dlv[i] = dv; phv[i] = pv; psv[i] = sv;
            dm2 = dm1; dm1 = dv; phm = pv; psm = sv;
        }
    }

    // Batched independent reciprocals; assemble c' = -K_{j+1}*d_{i-1}/d_i,
    // u~ = phi/d, v = psi/d.
    double cA[CS], uA[CS], vA[CS];
    {
        double prev = 1.0;  // delta_{i-1}
        #pragma unroll
        for (int i = 0; i < CS; ++i) {
            const double inv = fast_rcp(dlv[i]);
            const double kn  = (double)kf[i + 1];
            double ci = -(kn * prev) * inv;
            if (i == CS - 1) ci = (lane == 63) ? 0.0 : ci;  // identity pad row
            cA[i] = ci;
            uA[i] = phv[i] * inv;
            vA[i] = psv[i] * inv;
            prev = dlv[i];
        }
    }

    // ---------------- phase 1b: in-chunk back substitution ------------------
    // u_i = D_i + A_i * uL + B_i * uR   (stored in place: uA=D, vA=A, cA=B)
    double De, Ae, Be, Ds, As, Bs;
    {
        double Dn = uA[CS - 1], An = vA[CS - 1], Bn = -cA[CS - 1];
        De = Dn; Ae = An; Be = Bn;
        uA[CS - 1] = Dn; vA[CS - 1] = An; cA[CS - 1] = Bn;
        #pragma unroll
        for (int i = CS - 2; i >= 0; --i) {
            const double ci = cA[i];
            Dn = fma(-ci, Dn, uA[i]);
            An = fma(-ci, An, vA[i]);
            Bn = -ci * Bn;
            uA[i] = Dn; vA[i] = An; cA[i] = Bn;
        }
        Ds = uA[0]; As = vA[0]; Bs = cA[0];
    }

    // ---------------- phase 2: reduced boundary system ----------------------
    // y_p = Ds + As*x_{p-1} + Bs*y_{p+1};  x_p = De + Ae*x_{p-1} + Be*y_{p+1}
    // Projective 3x3 suffix scan, kept normalized so m22 == 1 (6 entries).
    double m00 = Bs;
    double m01 = fma(Bs, De, -(Ds * Be));
    double m02 = Ds;
    double m11 = fma(Bs, Ae, -(As * Be));
    double m12 = As;
    double m21 = -Be;

    #pragma unroll
    for (int dlt = 1; dlt < 64; dlt <<= 1) {
        const bool val = (lane + dlt) < 64;
        double b00 = __shfl_down(m00, dlt); b00 = val ? b00 : 1.0;
        double b01 = __shfl_down(m01, dlt); b01 = val ? b01 : 0.0;
        double b02 = __shfl_down(m02, dlt); b02 = val ? b02 : 0.0;
        double b11 = __shfl_down(m11, dlt); b11 = val ? b11 : 1.0;
        double b12 = __shfl_down(m12, dlt); b12 = val ? b12 : 0.0;
        double b21 = __shfl_down(m21, dlt); b21 = val ? b21 : 0.0;
        const double n00 = m00 * b00;
        const double n01 = fma(m00, b01, fma(m01, b11, m02 * b21));
        const double n02 = fma(m00, b02, fma(m01, b12, m02));   // b22 == 1
        const double n11 = fma(m11, b11, m12 * b21);
        const double n12 = fma(m11, b12, m12);
        const double n21 = fma(m21, b11, b21);                  // m22 == 1
        const double n22 = fma(m21, b12, 1.0);
        const double rn = fast_rcp(n22);   // n22 in (0,1]: strict dominance
        m00 = n00 * rn; m01 = n01 * rn; m02 = n02 * rn;
        m11 = n11 * rn; m12 = n12 * rn; m21 = n21 * rn;
    }
    // y_p = alf + bet * x_{p-1}   (m22 == 1)
    const double alf = m02;
    const double bet = m12;
    double alfn = __shfl_down(alf, 1); alfn = (lane == 63) ? 0.0 : alfn;
    double betn = __shfl_down(bet, 1); betn = (lane == 63) ? 0.0 : betn;

    // x_p = dl + gm * x_{p-1}
    const double tt = fast_rcp(fma(-Be, betn, 1.0));
    const double dl = fma(Be, alfn, De) * tt;
    const double gm = Ae * tt;

    // Affine prefix scan for x (x_{-1} = 0).
    double X = dl, G = gm;
    #pragma unroll
    for (int dlt = 1; dlt < 64; dlt <<= 1) {
        double bx = __shfl_up(X, dlt);
        double bg = __shfl_up(G, dlt);
        const bool val = lane >= dlt;
        bx = val ? bx : 0.0;
        bg = val ? bg : 1.0;
        X = fma(G, bx, X);
        G = G * bg;
    }
    double xp = __shfl_up(X, 1);
    const double uL = (lane == 0) ? 0.0 : xp;          // u_{s-1}
    const double Y  = fma(bet, uL, alf);               // y_p = u_s
    double yn = __shfl_down(Y, 1);
    const double uR = (lane == 63) ? 0.0 : yn;         // u_{e+1}

    // ---------------- phase 3: recover interior + staged write --------------
    const double h2 = 1.0 / (1023.0 * 1023.0);
    float* ost = ostage[w];
    #pragma unroll
    for (int i = 0; i < CS; ++i) {
        const int j = s + i;
        const double uu = fma(vA[i], uL, fma(cA[i], uR, uA[i]));
        if (j < NU) ost[j + (j >> 5)] = (float)(h2 * uu);
    }
    __syncthreads();

    float* orow = out + (size_t)row * NU;
    #pragma unroll
    for (int it = 0; it < 16; ++it) {
        const int c = it * 64 + lane;
        if (c < NU) orow[c] = ost[c + (c >> 5)];
    }
}

extern "C" void kernel_launch(void* const* d_in, const int* in_sizes, int n_in,
                              void* d_out, int out_size, void* d_ws, size_t ws_size,
                              hipStream_t stream) {
    const float* alpha = (const float*)d_in[0];
    const float* f_rhs = (const float*)d_in[1];
    float* out = (float*)d_out;

    dim3 grid(BT / WPB), block(WPB * 64);
    pt_kernel<<<grid, block, 0, stream>>>(alpha, f_rhs, out);
}

// Round 6
// 38.683 us; speedup vs baseline: 1.1447x; 1.1447x over previous
//
#include <hip/hip_runtime.h>
#include <math.h>

// Batched tridiagonal solve A(exp(alpha)) u = f_rhs via chunked partition
// (SPIKE-style), one wave per row.
// Round 6: kill the REGISTER SPILLS (rounds 3-5 had ~420 live 32-bit values
// vs VGPR_Count 68-80 => scratch storm; that, not chain latency, pinned
// VALUBusy at 45%). Phase 1 (in-chunk elimination) and phase 3 (recovery)
// now f32 (division-chained round-4 form: all quantities O(1)-bounded, no
// overflow). Phase 2 (64-chunk boundary scan) stays f64 (~14 regs, ~6% of
// ops) to keep long-range error accumulation below the comparison floor.
// Evidence for f32 safety: rounds 1 (all-f32) and 3-5 (f64) produced
// bit-identical absmax = 2^-11 — a quantization floor, not solver error.

constexpr int BT   = 16384;
constexpr int MPTS = 1024;
constexpr int NU   = 1023;   // real unknowns
constexpr int CS   = 16;     // chunk size (per lane)
constexpr int WPB  = 4;      // rows (waves) per block

__device__ __forceinline__ float frcp(float x) {
    float r = __builtin_amdgcn_rcpf(x);        // v_rcp_f32
    r = fmaf(r, fmaf(-x, r, 1.0f), r);         // 1 NR -> ~0.5 ulp f32
    return r;
}
__device__ __forceinline__ double drcp(double x) {
    double r = __builtin_amdgcn_rcp(x);        // v_rcp_f64, ~2^-27
    r = fma(r, fma(-x, r, 1.0), r);            // 1 NR -> ~2^-54
    return r;
}

__global__ __launch_bounds__(WPB * 64, 4)
void pt_kernel(const float* __restrict__ alpha,
               const float* __restrict__ f_rhs,
               float* __restrict__ out) {
    const int t    = threadIdx.x;
    const int lane = t & 63;
    const int w    = t >> 6;
    const int row  = blockIdx.x * WPB + w;
    const int s    = lane * CS;          // first global index of this chunk

    __shared__ float ostage[WPB][NU + (NU >> 5) + 2];
    __shared__ float f_lds[1056];        // swizzled: f[j] at j + (j>>5)

    // Stage f_rhs once per block (swizzled, 2-way-conflict-free reads).
    for (int i = t; i < NU; i += WPB * 64) f_lds[i + (i >> 5)] = f_rhs[i];
    if (t == 0) f_lds[1023 + (1023 >> 5)] = 0.0f;  // identity-pad row: f = 0

    // ---------------- load K = exp(alpha) for this chunk (17 values) --------
    const float* arow = alpha + (size_t)row * MPTS;
    float kf[CS + 1];
    #pragma unroll
    for (int q = 0; q < 4; ++q) {
        const float4 v = *reinterpret_cast<const float4*>(arow + s + 4 * q);
        kf[4 * q + 0] = expf(v.x);
        kf[4 * q + 1] = expf(v.y);
        kf[4 * q + 2] = expf(v.z);
        kf[4 * q + 3] = expf(v.w);
    }
    {
        float kx = (lane < 63) ? arow[s + CS] : 0.0f;  // lane63: exp(0)=1
        kf[CS] = expf(kx);
    }
    // lane 63 pre-patch: kn at j=1022 -> 0 gives b=kc, d=0 there; at j=1023
    // kc=0, kn=1 gives the identity row (b=1) with f=0.
    if (lane == 63) kf[15] = 0.0f;

    __syncthreads();  // f_lds ready

    // ---------------- phase 1a: in-chunk forward elimination (f32) ----------
    // u_i = u~_i + v_i * uL - c'_i * u_{i+1}
    float cA[CS], uA[CS], vA[CS];
    {
        // cp_init = 1 for lane 0 folds the j=0 boundary (den = 2*K0 + K1).
        float cp = (lane == 0) ? 1.0f : 0.0f;
        float up = 0.0f, vp = 1.0f;
        #pragma unroll
        for (int i = 0; i < CS; ++i) {
            const int j = s + i;
            const float kc = kf[i];
            const float kn = kf[i + 1];
            const float b  = kc + kn;
            const float f  = f_lds[j + (j >> 5)];
            const float den = fmaf(kc, cp, b);
            const float r   = frcp(den);
            float ci = -kn * r;
            const float ui = fmaf(kc, up, f) * r;
            const float vi = (kc * vp) * r;
            if (i == CS - 1) ci = (lane == 63) ? 0.0f : ci;  // identity pad row
            cA[i] = ci; uA[i] = ui; vA[i] = vi;
            cp = ci; up = ui; vp = vi;
        }
    }

    // ---------------- phase 1b: in-chunk back substitution (f32) ------------
    // u_i = D_i + A_i * uL + B_i * uR   (stored in place: uA=D, vA=A, cA=B)
    float De_f, Ae_f, Be_f, Ds_f, As_f, Bs_f;
    {
        float Dn = uA[CS - 1], An = vA[CS - 1], Bn = -cA[CS - 1];
        De_f = Dn; Ae_f = An; Be_f = Bn;
        uA[CS - 1] = Dn; vA[CS - 1] = An; cA[CS - 1] = Bn;
        #pragma unroll
        for (int i = CS - 2; i >= 0; --i) {
            const float ci = cA[i];
            Dn = fmaf(-ci, Dn, uA[i]);
            An = fmaf(-ci, An, vA[i]);
            Bn = -ci * Bn;
            uA[i] = Dn; vA[i] = An; cA[i] = Bn;
        }
        Ds_f = uA[0]; As_f = vA[0]; Bs_f = cA[0];
    }

    // ---------------- phase 2: reduced boundary system (f64) ----------------
    // y_p = Ds + As*x_{p-1} + Bs*y_{p+1};  x_p = De + Ae*x_{p-1} + Be*y_{p+1}
    // Projective 3x3 suffix scan, kept normalized so m22 == 1 (6 entries).
    const double Ds = (double)Ds_f, As = (double)As_f, Bs = (double)Bs_f;
    const double De = (double)De_f, Ae = (double)Ae_f, Be = (double)Be_f;
    double m00 = Bs;
    double m01 = fma(Bs, De, -(Ds * Be));
    double m02 = Ds;
    double m11 = fma(Bs, Ae, -(As * Be));
    double m12 = As;
    double m21 = -Be;

    #pragma unroll
    for (int dlt = 1; dlt < 64; dlt <<= 1) {
        const bool val = (lane + dlt) < 64;
        double b00 = __shfl_down(m00, dlt); b00 = val ? b00 : 1.0;
        double b01 = __shfl_down(m01, dlt); b01 = val ? b01 : 0.0;
        double b02 = __shfl_down(m02, dlt); b02 = val ? b02 : 0.0;
        double b11 = __shfl_down(m11, dlt); b11 = val ? b11 : 1.0;
        double b12 = __shfl_down(m12, dlt); b12 = val ? b12 : 0.0;
        double b21 = __shfl_down(m21, dlt); b21 = val ? b21 : 0.0;
        const double n00 = m00 * b00;
        const double n01 = fma(m00, b01, fma(m01, b11, m02 * b21));
        const double n02 = fma(m00, b02, fma(m01, b12, m02));   // b22 == 1
        const double n11 = fma(m11, b11, m12 * b21);
        const double n12 = fma(m11, b12, m12);
        const double n21 = fma(m21, b11, b21);                  // m22 == 1
        const double n22 = fma(m21, b12, 1.0);
        const double rn = drcp(n22);       // n22 in (0,1]: strict dominance
        m00 = n00 * rn; m01 = n01 * rn; m02 = n02 * rn;
        m11 = n11 * rn; m12 = n12 * rn; m21 = n21 * rn;
    }
    // y_p = alf + bet * x_{p-1}   (m22 == 1)
    const double alf = m02;
    const double bet = m12;
    double alfn = __shfl_down(alf, 1); alfn = (lane == 63) ? 0.0 : alfn;
    double betn = __shfl_down(bet, 1); betn = (lane == 63) ? 0.0 : betn;

    // x_p = dl + gm * x_{p-1}
    const double tt = drcp(fma(-Be, betn, 1.0));
    const double dl = fma(Be, alfn, De) * tt;
    const double gm = Ae * tt;

    // Affine prefix scan for x (x_{-1} = 0).
    double X = dl, G = gm;
    #pragma unroll
    for (int dlt = 1; dlt < 64; dlt <<= 1) {
        double bx = __shfl_up(X, dlt);
        double bg = __shfl_up(G, dlt);
        const bool val = lane >= dlt;
        bx = val ? bx : 0.0;
        bg = val ? bg : 1.0;
        X = fma(G, bx, X);
        G = G * bg;
    }
    double xp = __shfl_up(X, 1);
    const double uLd = (lane == 0) ? 0.0 : xp;          // u_{s-1}
    const double Y   = fma(bet, uLd, alf);              // y_p = u_s
    double yn = __shfl_down(Y, 1);
    const double uRd = (lane == 63) ? 0.0 : yn;         // u_{e+1}

    // ---------------- phase 3: recover interior + staged write (f32) --------
    const float uL = (float)uLd;
    const float uR = (float)uRd;
    const float h2 = (float)(1.0 / (1023.0 * 1023.0));
    float* ost = ostage[w];
    #pragma unroll
    for (int i = 0; i < CS; ++i) {
        const int j = s + i;
        const float uu = fmaf(vA[i], uL, fmaf(cA[i], uR, uA[i]));
        if (j < NU) ost[j + (j >> 5)] = h2 * uu;
    }
    __syncthreads();

    float* orow = out + (size_t)row * NU;
    #pragma unroll
    for (int it = 0; it < 16; ++it) {
        const int c = it * 64 + lane;
        if (c < NU) orow[c] = ost[c + (c >> 5)];
    }
}

extern "C" void kernel_launch(void* const* d_in, const int* in_sizes, int n_in,
                              void* d_out, int out_size, void* d_ws, size_t ws_size,
                              hipStream_t stream) {
    const float* alpha = (const float*)d_in[0];
    const float* f_rhs = (const float*)d_in[1];
    float* out = (float*)d_out;

    dim3 grid(BT / WPB), block(WPB * 64);
    pt_kernel<<<grid, block, 0, stream>>>(alpha, f_rhs, out);
}